// Round 3
// baseline (302.407 us; speedup 1.0000x reference)
//
#include <hip/hip_runtime.h>
#include <hip/hip_bf16.h>

// TT-linear: out(8192x4096) = x @ W, W from TT cores g1,g2.
// (1) prep: cvt x->bf16 + build W^T bf16 (merged), (2) 256x256 MFMA GEMM,
//     BK=32, TRIPLE-buffered LDS (96KB), 2 phases/K-tile, vmcnt(4) pipeline.

#define TOKENS 8192
#define KDIM 4096
#define NDIM 4096

typedef __attribute__((ext_vector_type(8))) __bf16 bf16x8;
typedef __attribute__((ext_vector_type(4))) float f32x4;
typedef __attribute__((ext_vector_type(8))) unsigned short u16x8;

typedef __attribute__((address_space(1))) unsigned int as1_uint;
typedef __attribute__((address_space(3))) unsigned int as3_uint;

#define GLOAD_LDS16(gp, lp) \
  __builtin_amdgcn_global_load_lds((as1_uint*)(void*)(gp), (as3_uint*)(void*)(lp), 16, 0, 0)

#define BAR() asm volatile("s_barrier" ::: "memory")
#define LGKM0() asm volatile("s_waitcnt lgkmcnt(0)" ::: "memory")
#define VMCNT4() asm volatile("s_waitcnt vmcnt(4)" ::: "memory")
#define VMCNT0() asm volatile("s_waitcnt vmcnt(0)" ::: "memory")

__device__ inline unsigned short f2bf(float f) {
  __hip_bfloat16 h = __float2bfloat16(f);
  return __builtin_bit_cast(unsigned short, h);
}

// ---------------- Kernel 1: merged prep (cvt x -> bf16 ; build Wt[n][k] bf16) ----------------
// blocks [0, 16384): cvt 2048 x-elements each; blocks [16384, 20480): build one n-column of Wt.
__global__ __launch_bounds__(256) void prep_kernel(const float* __restrict__ x,
                                                   const float* __restrict__ g1,
                                                   const float* __restrict__ g2,
                                                   unsigned short* __restrict__ xb,
                                                   unsigned short* __restrict__ wt) {
  __shared__ float a_s[64 * 16];  // [m1][r] for fixed n1
  __shared__ float b_s[16 * 64];  // [r][m2] for fixed n2
  const int bid = blockIdx.x;
  const int t = threadIdx.x;

  if (bid < 16384) {
    // ---- cvt path ----
    size_t i = (size_t)bid * 256 + t;
    const float4* p = reinterpret_cast<const float4*>(x) + i * 2;
    float4 v0 = p[0];
    float4 v1 = p[1];
    u16x8 u;
    u[0] = f2bf(v0.x); u[1] = f2bf(v0.y); u[2] = f2bf(v0.z); u[3] = f2bf(v0.w);
    u[4] = f2bf(v1.x); u[5] = f2bf(v1.y); u[6] = f2bf(v1.z); u[7] = f2bf(v1.w);
    reinterpret_cast<u16x8*>(xb)[i] = u;
    return;
  }

  // ---- build path: Wt[n][k] = sum_r g1[0,k>>6,n>>6,r] * g2[r,k&63,n&63,0] ----
  const int n = bid - 16384;
  const int n1 = n >> 6, n2 = n & 63;
  for (int e = t; e < 1024; e += 256) {
    int m1 = e >> 4, r = e & 15;
    a_s[e] = g1[m1 * 1024 + n1 * 16 + r];
  }
  for (int e = t; e < 1024; e += 256) {
    int r = e >> 6, m2 = e & 63;
    b_s[e] = g2[r * 4096 + m2 * 64 + n2];
  }
  __syncthreads();

  unsigned short loc[16];
  const int kbase = t * 16;
#pragma unroll
  for (int kk = 0; kk < 16; ++kk) {
    int k = kbase + kk;
    int m1 = k >> 6, m2 = k & 63;
    float acc = 0.f;
#pragma unroll
    for (int r = 0; r < 16; ++r) acc += a_s[m1 * 16 + r] * b_s[r * 64 + m2];
    loc[kk] = f2bf(acc);
  }
  u16x8* dst = reinterpret_cast<u16x8*>(wt + (size_t)n * KDIM + kbase);
  dst[0] = *reinterpret_cast<u16x8*>(&loc[0]);
  dst[1] = *reinterpret_cast<u16x8*>(&loc[8]);
}

// ---------------- Kernel 2: 256x256 GEMM, BK=32, triple-buffered, 2 phases/K-tile ----------------
// out[m][n] = sum_k Xb[m][k] * Wt[n][k].
// LDS buffer c (c=0,1,2) at c*32768: A tile [256][32]bf16 at +0, B tile at +16384.
// Row = 64B = 4 chunks of 16B; swizzle: chunk_lds = chunk ^ ((row>>1)&3).
// Pipeline: iter s reads tile s from buf s%3; stages tile s+2 into buf (s+2)%3
// (A in ph1, B in ph2); vmcnt(4) at ph2 drains tile s+1 (never below 4 in-flight).
__global__ __launch_bounds__(512, 2) void gemm_kernel(const unsigned short* __restrict__ Xb,
                                                      const unsigned short* __restrict__ Wt,
                                                      float* __restrict__ out) {
  __shared__ __align__(16) char lds[98304];

  const int t = threadIdx.x;
  const int lane = t & 63;
  const int wave = t >> 6;   // 0..7
  const int wm = wave >> 2;  // 0..1 : 128 output rows
  const int wn = wave & 3;   // 0..3 : 64 output cols

  // XCD-bijective swizzle: 512 blocks, 512 % 8 == 0
  const int bid = blockIdx.x;
  const int wg = (bid & 7) * 64 + (bid >> 3);
  const int bm = wg >> 4, bn = wg & 15;  // 32 x 16 tile grid
  const int m0 = bm << 8, n0 = bn << 8;

  // staging: thread t covers 16B slot t of an 8KB half-tile (128 rows x 64B):
  // row_local = t>>2, chunk_lds = t&3, inverse-swizzled source chunk = (t&3)^((t>>3)&3).
  const int srow = t >> 2;
  const int csrc = (t & 3) ^ ((t >> 3) & 3);
  const unsigned short* aS = Xb + (size_t)(m0 + srow) * KDIM + csrc * 8;
  const unsigned short* bS = Wt + (size_t)(n0 + srow) * KDIM + csrc * 8;
  const int ldsW = wave << 10;  // wave-uniform 1KB slot

#define STG_A(kt, bufB, h) \
  GLOAD_LDS16(aS + (size_t)(h) * 128 * KDIM + (size_t)(kt) * 32, lds + (bufB) + (h) * 8192 + ldsW)
#define STG_B(kt, bufB, h) \
  GLOAD_LDS16(bS + (size_t)(h) * 128 * KDIM + (size_t)(kt) * 32, lds + (bufB) + 16384 + (h) * 8192 + ldsW)

  // fragment reads: row r = fragBase + (lane&15), want global chunk c = lane>>4:
  // chunk_lds = (lane>>4) ^ ((r>>1)&3) = (lane>>4) ^ ((lane>>1)&3)  (fragBase mult of 16)
  const int laneOff = (lane & 15) * 64 + (((lane >> 4) ^ ((lane >> 1) & 3)) << 4);
  const int aBase = wm * 8192 + laneOff;          // + i*1024 + bufB
  const int bBase = 16384 + wn * 4096 + laneOff;  // + j*1024 + bufB

#define RA(i) (*(const bf16x8*)(lds + rbB + aBase + (i) * 1024))
#define RB(j) (*(const bf16x8*)(lds + rbB + bBase + (j) * 1024))
#define MF(i, j, A, B) acc[i][j] = __builtin_amdgcn_mfma_f32_16x16x32_bf16((A), (B), acc[i][j], 0, 0, 0)

  f32x4 acc[8][4];
#pragma unroll
  for (int i = 0; i < 8; ++i)
#pragma unroll
    for (int j = 0; j < 4; ++j) acc[i][j] = (f32x4){0.f, 0.f, 0.f, 0.f};

  // ---- prologue: tile0 -> buf0, tile1 -> buf1; drain tile0, keep tile1 in flight ----
  STG_A(0, 0, 0); STG_A(0, 0, 1); STG_B(0, 0, 0); STG_B(0, 0, 1);
  STG_A(1, 32768, 0); STG_A(1, 32768, 1); STG_B(1, 32768, 0); STG_B(1, 32768, 1);
  VMCNT4();
  BAR();

  int rbB = 0;      // read-buffer byte base  (s % 3)
  int sbB = 65536;  // stage-buffer byte base ((s+2) % 3)

#pragma unroll 1
  for (int s = 0; s < 128; ++s) {
    // ---- phase 1: read A i0-3 + B j0-3 ; stage A(s+2) ; MFMA i0-3 ----
    bf16x8 a0 = RA(0), a1 = RA(1), a2 = RA(2), a3 = RA(3);
    bf16x8 b0 = RB(0), b1 = RB(1), b2 = RB(2), b3 = RB(3);
    if (s < 126) { STG_A(s + 2, sbB, 0); STG_A(s + 2, sbB, 1); }
    BAR(); LGKM0();
    __builtin_amdgcn_s_setprio(1);
    MF(0, 0, a0, b0); MF(0, 1, a0, b1); MF(0, 2, a0, b2); MF(0, 3, a0, b3);
    MF(1, 0, a1, b0); MF(1, 1, a1, b1); MF(1, 2, a1, b2); MF(1, 3, a1, b3);
    MF(2, 0, a2, b0); MF(2, 1, a2, b1); MF(2, 2, a2, b2); MF(2, 3, a2, b3);
    MF(3, 0, a3, b0); MF(3, 1, a3, b1); MF(3, 2, a3, b2); MF(3, 3, a3, b3);
    __builtin_amdgcn_s_setprio(0);
    BAR();

    // ---- phase 2: read A i4-7 ; stage B(s+2) ; vmcnt -> tile s+1 resident ; MFMA i4-7 ----
    bf16x8 a4 = RA(4), a5 = RA(5), a6 = RA(6), a7 = RA(7);
    if (s < 126) {
      STG_B(s + 2, sbB, 0); STG_B(s + 2, sbB, 1);
      VMCNT4();
    } else {
      VMCNT0();
    }
    BAR(); LGKM0();
    __builtin_amdgcn_s_setprio(1);
    MF(4, 0, a4, b0); MF(4, 1, a4, b1); MF(4, 2, a4, b2); MF(4, 3, a4, b3);
    MF(5, 0, a5, b0); MF(5, 1, a5, b1); MF(5, 2, a5, b2); MF(5, 3, a5, b3);
    MF(6, 0, a6, b0); MF(6, 1, a6, b1); MF(6, 2, a6, b2); MF(6, 3, a6, b3);
    MF(7, 0, a7, b0); MF(7, 1, a7, b1); MF(7, 2, a7, b2); MF(7, 3, a7, b3);
    __builtin_amdgcn_s_setprio(0);
    BAR();

    rbB += 32768; if (rbB == 98304) rbB = 0;
    sbB += 32768; if (sbB == 98304) sbB = 0;
  }

  // ---- epilogue: C/D layout col = lane&15, row = (lane>>4)*4 + q ----
  const int crow = (lane >> 4) << 2;
  const int ccol = lane & 15;
#pragma unroll
  for (int i = 0; i < 8; ++i) {
#pragma unroll
    for (int j = 0; j < 4; ++j) {
      size_t base = (size_t)(m0 + wm * 128 + i * 16 + crow) * NDIM + (n0 + wn * 64 + j * 16 + ccol);
#pragma unroll
      for (int q = 0; q < 4; ++q) out[base + (size_t)q * NDIM] = acc[i][j][q];
    }
  }
}

extern "C" void kernel_launch(void* const* d_in, const int* in_sizes, int n_in,
                              void* d_out, int out_size, void* d_ws, size_t ws_size,
                              hipStream_t stream) {
  const float* x = (const float*)d_in[0];
  const float* g1 = (const float*)d_in[1];
  const float* g2 = (const float*)d_in[2];
  float* out = (float*)d_out;

  unsigned short* Wt = (unsigned short*)d_ws;
  unsigned short* Xb = (unsigned short*)d_ws + (size_t)KDIM * NDIM;

  prep_kernel<<<16384 + NDIM, 256, 0, stream>>>(x, g1, g2, Xb, Wt);
  gemm_kernel<<<(TOKENS / 256) * (NDIM / 256), 512, 0, stream>>>(Xb, Wt, out);
}